// Round 11
// baseline (53.306 us; speedup 1.0000x reference)
//
#include <hip/hip_runtime.h>

// SSIM loss, fused. in: f32 (16,3,512,512) x2; out: f32[16].
//
// r10 structure + band-major intra-XCD dispatch.
// 1 wave owns a 512-col x RPS-row strip, 8 cols/lane. Vertical sliding
// 11-row column sums {s1,s2,sp,sq} in registers; per output row publish own
// col-quads to sigma-permuted wave-private LDS (8x ds_write_b128,
// conflict-free), read 10 halo quads (b128), slide window using own sums
// from registers. No __syncthreads. NEW row prefetched one iter ahead;
// OLD row re-read (L2 hit). Banked double atomics.
//
// r11 change: q = sblk*GRP + g  (band-major) instead of g*SBLK + sblk.
// r10 serialized each XCD's 6 images (one image's 26 blocks in flight ->
// 3 waves/CU, 16% occupancy). Band-major co-dispatches the same row band
// of all 6 images: all 156 blocks/XCD resident (LDS cap 160), concurrent
// working set = one band x 6 images (~1.5MB) fits 4MB L2. Keeps r10's
// image->XCD pinning (FETCH 85MB) while restoring ~4x concurrency.

namespace {
constexpr int BATCH = 16;
constexpr int CHAN  = 3;
constexpr int HDIM  = 512;
constexpr int WDIM  = 512;
constexpr int WIN   = 11;
constexpr int HO    = HDIM - WIN + 1;   // 502
constexpr int WO    = WDIM - WIN + 1;   // 502
constexpr int RPS   = 5;
constexpr int STRIPS = (HO + RPS - 1) / RPS;     // 101 real strips
constexpr int WPB   = 4;                          // waves per block
constexpr int NTHR  = WPB * 64;
constexpr int SBLK  = (STRIPS + WPB - 1) / WPB;   // 26 strip-blocks per image
constexpr int NIMG  = BATCH * CHAN;               // 48
constexpr int NXCD  = 8;
constexpr int GRP   = NIMG / NXCD;                // 6 images per XCD
constexpr int NBLK  = NIMG * SBLK;                // 1248
constexpr int NBANK = 16;
// scale-folded constants: C*121^2 (121^4 cancels in n/d)
constexpr float K1 = 6.5025f  * 14641.0f;
constexpr float K2 = 58.5225f * 14641.0f;
constexpr float W2F = 121.0f;
}

__global__ __launch_bounds__(NTHR) void ssim_main(
    const float* __restrict__ g1, const float* __restrict__ g2,
    double* __restrict__ ws) {
  __shared__ float4 lds4[WPB * 512];               // 32 KB

  const int t   = threadIdx.x & 63;
  const int wv  = threadIdx.x >> 6;

  // XCD-pinned, band-major decode: xcd = img%8; bands co-dispatch.
  const int xcd  = blockIdx.x & (NXCD - 1);
  const int q    = blockIdx.x >> 3;        // 0 .. GRP*SBLK-1
  const int g    = q % GRP;                // image within XCD (fast)
  const int sblk = q / GRP;                // band (slow)
  const int img  = g * NXCD + xcd;         // 0..47
  const int strip = sblk * WPB + wv;
  if (strip >= STRIPS) return;             // 3 pad waves per image

  const int b   = img / CHAN;
  const int r0  = strip * RPS;
  const int r1  = min(r0 + RPS, HO);

  const int cb = 8 * t;                    // first owned col
  float4* __restrict__ W  = lds4 + wv * 512;
  const float4* __restrict__ Rd = lds4 + wv * 512;
  const int tp1 = (t + 1) & 63;            // halo lanes (wrap -> masked cols)
  const int tp2 = (t + 2) & 63;

  const float* __restrict__ p1 = g1 + (size_t)img * HDIM * WDIM + cb;
  const float* __restrict__ p2 = g2 + (size_t)img * HDIM * WDIM + cb;

  float s1[8], s2[8], sp[8], sq[8];
#pragma unroll
  for (int k = 0; k < 8; ++k) s1[k] = s2[k] = sp[k] = sq[k] = 0.f;

  float4 au0, au1, av0, av1, bu0, bu1, bv0, bv1;
  auto loadA = [&](int row) {
    const float* q1 = p1 + (size_t)row * WDIM;
    const float* q2 = p2 + (size_t)row * WDIM;
    au0 = *(const float4*)q1; au1 = *(const float4*)(q1 + 4);
    av0 = *(const float4*)q2; av1 = *(const float4*)(q2 + 4);
  };
  auto loadB = [&](int row) {
    const float* q1 = p1 + (size_t)row * WDIM;
    const float* q2 = p2 + (size_t)row * WDIM;
    bu0 = *(const float4*)q1; bu1 = *(const float4*)(q1 + 4);
    bv0 = *(const float4*)q2; bv1 = *(const float4*)(q2 + 4);
  };
  auto accum = [&]() {
    float uu[8] = {au0.x, au0.y, au0.z, au0.w, au1.x, au1.y, au1.z, au1.w};
    float vv[8] = {av0.x, av0.y, av0.z, av0.w, av1.x, av1.y, av1.z, av1.w};
#pragma unroll
    for (int k = 0; k < 8; ++k) {
      float x = uu[k], y = vv[k];
      s1[k] += x;
      s2[k] += y;
      sp[k] = fmaf(x, y, sp[k]);
      sq[k] = fmaf(x, x, sq[k]);
      sq[k] = fmaf(y, y, sq[k]);
    }
  };
  auto desum = [&]() {
    float uu[8] = {bu0.x, bu0.y, bu0.z, bu0.w, bu1.x, bu1.y, bu1.z, bu1.w};
    float vv[8] = {bv0.x, bv0.y, bv0.z, bv0.w, bv1.x, bv1.y, bv1.z, bv1.w};
#pragma unroll
    for (int k = 0; k < 8; ++k) {
      float x = uu[k], y = vv[k];
      s1[k] -= x;
      s2[k] -= y;
      sp[k] = fmaf(x, -y, sp[k]);
      sq[k] = fmaf(x, -x, sq[k]);
      sq[k] = fmaf(y, -y, sq[k]);
    }
  };

  // ---- warm-up: accumulate rows r0 .. r0+9, 2-deep pipelined ----
  loadA(r0);
  loadB(r0 + 1);
#pragma unroll
  for (int dy = 0; dy < 10; dy += 2) {
    accum();
    loadA(r0 + dy + 2);      // dy=8 -> loads row r0+10 = first NEW
    { float4 tu0 = au0, tu1 = au1, tv0 = av0, tv1 = av1;
      au0 = bu0; au1 = bu1; av0 = bv0; av1 = bv1;
      accum();
      au0 = tu0; au1 = tu1; av0 = tv0; av1 = tv1; }
    if (dy < 8) loadB(r0 + dy + 3);
  }
  loadB(r0);                 // first OLD row

  // ---- main loop ----
  float acc = 0.f;
  for (int r = r0; r < r1; ++r) {
    accum();                              // window = rows [r, r+10]
    loadA(min(r + WIN, HDIM - 1));        // prefetch next NEW

    // publish own 8 col-quads (consecutive lanes contiguous: conflict-free)
#pragma unroll
    for (int i = 0; i < 8; ++i)
      W[i * 64 + t] = make_float4(s1[i], s2[i], sp[i], sq[i]);
    asm volatile("s_waitcnt lgkmcnt(0)" ::: "memory");

    // halo: cols cb+8+m. m<8: quad m*64+(t+1); m=8,9: (m-8)*64+(t+2)
    float4 cN[10];
#pragma unroll
    for (int m = 0; m < 8; ++m) cN[m] = Rd[m * 64 + tp1];
    cN[8] = Rd[tp2];
    cN[9] = Rd[64 + tp2];

    float w1 = ((s1[0] + s1[1]) + (s1[2] + s1[3])) +
               ((s1[4] + s1[5]) + (s1[6] + s1[7])) +
               ((cN[0].x + cN[1].x) + cN[2].x);
    float w2 = ((s2[0] + s2[1]) + (s2[2] + s2[3])) +
               ((s2[4] + s2[5]) + (s2[6] + s2[7])) +
               ((cN[0].y + cN[1].y) + cN[2].y);
    float wp = ((sp[0] + sp[1]) + (sp[2] + sp[3])) +
               ((sp[4] + sp[5]) + (sp[6] + sp[7])) +
               ((cN[0].z + cN[1].z) + cN[2].z);
    float wq = ((sq[0] + sq[1]) + (sq[2] + sq[3])) +
               ((sq[4] + sq[5]) + (sq[6] + sq[7])) +
               ((cN[0].w + cN[1].w) + cN[2].w);

#pragma unroll
    for (int j = 0; j < 8; ++j) {
      if (j > 0) {
        w1 = (w1 - s1[j - 1]) + cN[j + 2].x;
        w2 = (w2 - s2[j - 1]) + cN[j + 2].y;
        wp = (wp - sp[j - 1]) + cN[j + 2].z;
        wq = (wq - sq[j - 1]) + cN[j + 2].w;
      }
      // scale-folded SSIM (121^4 cancels in n/d)
      float s12 = w1 * w2;
      float msq = fmaf(w1, w1, w2 * w2);
      float N1  = fmaf(2.f, s12, K1);
      float N2  = fmaf(2.f, fmaf(W2F, wp, -s12), K2);
      float D1  = msq + K1;
      float D2  = fmaf(W2F, wq, -msq) + K2;
      float val = (N1 * N2) * __builtin_amdgcn_rcpf(D1 * D2);
      acc += (cb + j < WO) ? val : 0.f;
    }

    desum();                              // slide out row r
    loadB(r + 1);                         // prefetch next OLD (L2 hit)
  }

  // wave reduction (cold), banked double atomic
#pragma unroll
  for (int off = 32; off > 0; off >>= 1) acc += __shfl_down(acc, off, 64);
  if (t == 0) {
    int bank = (img * STRIPS + strip) & (NBANK - 1);
    atomicAdd(&ws[b * NBANK + bank], (double)acc);
  }
}

__global__ void ssim_finalize(const double* __restrict__ ws,
                              float* __restrict__ out) {
  int i = threadIdx.x;
  if (i < BATCH) {
    double s = 0.0;
#pragma unroll
    for (int k = 0; k < NBANK; ++k) s += ws[i * NBANK + k];
    out[i] = (float)(1.0 - s / ((double)CHAN * HO * WO));
  }
}

extern "C" void kernel_launch(void* const* d_in, const int* in_sizes, int n_in,
                              void* d_out, int out_size, void* d_ws,
                              size_t ws_size, hipStream_t stream) {
  const float* img1 = (const float*)d_in[0];
  const float* img2 = (const float*)d_in[1];
  float* out = (float*)d_out;
  double* ws = (double*)d_ws;

  hipMemsetAsync(d_ws, 0, BATCH * NBANK * sizeof(double), stream);
  ssim_main<<<dim3(NBLK), NTHR, 0, stream>>>(img1, img2, ws);
  ssim_finalize<<<1, 64, 0, stream>>>(ws, out);
}